// Round 10
// baseline (380.561 us; speedup 1.0000x reference)
//
#include <hip/hip_runtime.h>
#include <math.h>

typedef __bf16 bf16_t;
typedef __attribute__((ext_vector_type(4))) __bf16 bf16x4;
typedef __attribute__((ext_vector_type(8))) __bf16 bf16x8;
typedef __attribute__((ext_vector_type(4))) float f32x4;

#define BTILE 8192      // edges per passB tile
#define BSH   9         // bucket shift: 512 nodes per bucket
#define CAP   18432     // record capacity per bucket (mean 16384 + 16 sigma)

// ---------------- fills ----------------

__global__ void k_fill_i(int* __restrict__ p, int v, int n) {
    int i = blockIdx.x * blockDim.x + threadIdx.x;
    int s = gridDim.x * blockDim.x;
    for (; i < n; i += s) p[i] = v;
}

// ---------------- Pass B: bin edges into capacity-padded buckets ----------------
// record.x = (dst&511)<<17 | src  (src < 2^17), record.y = ew bits

__global__ __launch_bounds__(512) void k_passB(const int* __restrict__ ei,
        const float* __restrict__ ew, int* __restrict__ bcur,
        int2* __restrict__ rec, int E, int NB) {
    __shared__ int lhist[256];
    __shared__ int base[256];
    const int* dstp = ei + E;
    int tile0 = blockIdx.x * BTILE;
    int t = threadIdx.x;
    if (t < 256) lhist[t] = 0;
    __syncthreads();
    int rank[BTILE / 512];
#pragma unroll
    for (int j = 0; j < BTILE / 512; ++j) {
        int e = tile0 + j * 512 + t;
        if (e < E) rank[j] = atomicAdd(&lhist[dstp[e] >> BSH], 1);
    }
    __syncthreads();
    if (t < NB) {
        int c = lhist[t];
        base[t] = c ? atomicAdd(&bcur[t], c) : 0;
    }
    __syncthreads();
#pragma unroll
    for (int j = 0; j < BTILE / 512; ++j) {
        int e = tile0 + j * 512 + t;
        if (e < E) {
            int d = dstp[e];
            int b = d >> BSH;
            rec[(size_t)b * CAP + base[b] + rank[j]] =
                make_int2(((d & 511) << 17) | ei[e], __float_as_int(ew[e]));
        }
    }
}

// ---------------- Pass C: per-bucket counting sort -> meta, rbeg/rend, dinv ----

__global__ __launch_bounds__(1024) void k_passC(const int2* __restrict__ rec,
        const int* __restrict__ bcur, int* __restrict__ rbeg, int* __restrict__ rend,
        float* __restrict__ dinv, int2* __restrict__ meta, int N) {
    __shared__ int   nh[512];
    __shared__ float sw[512];
    __shared__ int   offs[512];
    __shared__ int   cur[512];
    __shared__ int   scn[512];
    int b = blockIdx.x, t = threadIdx.x;
    if (t < 512) { nh[t] = 0; sw[t] = 0.f; cur[t] = 0; }
    __syncthreads();
    int len = bcur[b];
    size_t rs = (size_t)b * CAP;
    for (int i = t; i < len; i += 1024) {
        int2 r = rec[rs + i];
        int dl = r.x >> 17;
        atomicAdd(&nh[dl], 1);
        atomicAdd(&sw[dl], __int_as_float(r.y));
    }
    __syncthreads();
    if (t < 512) scn[t] = nh[t];
    __syncthreads();
    for (int off = 1; off < 512; off <<= 1) {
        int v = (t >= off && t < 512) ? scn[t - off] : 0;
        __syncthreads();
        if (t < 512) scn[t] += v;
        __syncthreads();
    }
    if (t < 512) {
        offs[t] = scn[t] - nh[t];
        int node = (b << BSH) + t;
        if (node < N) {
            int rb = (int)rs + offs[t];
            rbeg[node] = rb;
            rend[node] = rb + nh[t];
            dinv[node] = rsqrtf(1.f + sw[t]);
        }
    }
    __syncthreads();
    for (int i = t; i < len; i += 1024) {
        int2 r = rec[rs + i];
        int dl = r.x >> 17;
        int pos = atomicAdd(&cur[dl], 1);
        meta[rs + offs[dl] + pos] = make_int2(r.x & 0x1FFFF, r.y);
    }
}

// ---------------- MFMA GEMM: out[n][f] = dinv[n] * (X[n][:] @ W[:][f]) ----------------

template <int K, bool A_F32>
__global__ __launch_bounds__(256) void k_gemm_mfma(
        const void* __restrict__ Xv, const float* __restrict__ W,
        const float* __restrict__ dinv, bf16_t* __restrict__ outb, int ntiles) {
    __shared__ bf16_t sWt[64 * K];              // transposed W: sWt[c*K + k]
    for (int idx = threadIdx.x; idx < K * 64; idx += blockDim.x) {
        int k = idx >> 6, c = idx & 63;
        sWt[c * K + k] = (bf16_t)W[idx];
    }
    __syncthreads();

    int lane = threadIdx.x & 63;
    int wid  = threadIdx.x >> 6;
    int colbase = wid * 16;
    int lm = lane & 15;
    int lk = lane >> 4;

    bf16x8 bfrag[K / 32];
#pragma unroll
    for (int ks = 0; ks < K / 32; ++ks)
        bfrag[ks] = *(const bf16x8*)&sWt[(colbase + lm) * K + ks * 32 + lk * 8];

    const float*  Xf = (const float*)Xv;
    const bf16_t* Xb = (const bf16_t*)Xv;

    for (int t = blockIdx.x; t < ntiles; t += gridDim.x) {
        f32x4 acc = {0.f, 0.f, 0.f, 0.f};
        size_t rowoff = (size_t)(t * 16 + lm) * K + lk * 8;
#pragma unroll
        for (int ks = 0; ks < K / 32; ++ks) {
            bf16x8 afrag;
            if (A_F32) {
                float4 v0 = *(const float4*)(Xf + rowoff + ks * 32);
                float4 v1 = *(const float4*)(Xf + rowoff + ks * 32 + 4);
                afrag[0] = (bf16_t)v0.x; afrag[1] = (bf16_t)v0.y;
                afrag[2] = (bf16_t)v0.z; afrag[3] = (bf16_t)v0.w;
                afrag[4] = (bf16_t)v1.x; afrag[5] = (bf16_t)v1.y;
                afrag[6] = (bf16_t)v1.z; afrag[7] = (bf16_t)v1.w;
            } else {
                afrag = *(const bf16x8*)(Xb + rowoff + ks * 32);
            }
            acc = __builtin_amdgcn_mfma_f32_16x16x32_bf16(afrag, bfrag[ks], acc, 0, 0, 0);
        }
#pragma unroll
        for (int r = 0; r < 4; ++r) {
            int row = t * 16 + lk * 4 + r;
            outb[(size_t)row * 64 + colbase + lm] = (bf16_t)(acc[r] * dinv[row]);
        }
    }
}

// ---------------- fused gather-conv, 4 nodes/wave, branchless pipelined loop ----

template <bool F32OUT>
__global__ __launch_bounds__(256) void k_conv4(
        const bf16_t* __restrict__ P, const int* __restrict__ rbeg,
        const int* __restrict__ rend,
        const int2* __restrict__ meta, const float* __restrict__ dinv,
        const float* __restrict__ b, bf16_t* __restrict__ Qb,
        float* __restrict__ Qf, int n_nodes) {
    int lane = threadIdx.x & 63;
    int g  = lane >> 4;
    int fl = lane & 15;
    int wave  = blockIdx.x * (blockDim.x >> 6) + (threadIdx.x >> 6);
    int nwave = gridDim.x * (blockDim.x >> 6);
    int nquads = (n_nodes + 3) >> 2;

    float4 bv = *(const float4*)(b + fl * 4);

    for (int q = wave; q < nquads; q += nwave) {
        int nd = q * 4 + g;
        bool act = nd < n_nodes;
        int ndc = act ? nd : 0;

        int beg = rbeg[ndc];
        int end = act ? rend[ndc] : beg;

        bf16x4 sv = *(const bf16x4*)(P + (size_t)ndc * 64 + fl * 4);
        float a0 = (float)sv[0], a1 = (float)sv[1], a2 = (float)sv[2], a3 = (float)sv[3];
        float c0 = 0.f, c1 = 0.f, c2 = 0.f, c3 = 0.f;

        // wave-uniform loop bound: max row length over the 4 groups
        int len = end - beg;
        int ml = len;
        ml = max(ml, __shfl_xor(ml, 16, 64));
        ml = max(ml, __shfl_xor(ml, 32, 64));

#pragma unroll 2
        for (int k = 0; k < ml; k += 2) {
            int e0 = beg + k, e1 = e0 + 1;
            bool v0 = e0 < end, v1 = e1 < end;
            int i0 = v0 ? e0 : 0;          // clamp to a real record: no branch,
            int i1 = v1 ? e1 : 0;          // dummy load is L1-hot broadcast
            int2 m0 = meta[i0];
            int2 m1 = meta[i1];
            float w0 = v0 ? __int_as_float(m0.y) : 0.f;
            float w1 = v1 ? __int_as_float(m1.y) : 0.f;
            bf16x4 p0 = *(const bf16x4*)(P + (size_t)m0.x * 64 + fl * 4);
            bf16x4 p1 = *(const bf16x4*)(P + (size_t)m1.x * 64 + fl * 4);
            a0 = fmaf(w0, (float)p0[0], a0);
            a1 = fmaf(w0, (float)p0[1], a1);
            a2 = fmaf(w0, (float)p0[2], a2);
            a3 = fmaf(w0, (float)p0[3], a3);
            c0 = fmaf(w1, (float)p1[0], c0);
            c1 = fmaf(w1, (float)p1[1], c1);
            c2 = fmaf(w1, (float)p1[2], c2);
            c3 = fmaf(w1, (float)p1[3], c3);
        }
        a0 += c0; a1 += c1; a2 += c2; a3 += c3;

        float dn = dinv[ndc];
        a0 = fmaf(dn, a0, bv.x);
        a1 = fmaf(dn, a1, bv.y);
        a2 = fmaf(dn, a2, bv.z);
        a3 = fmaf(dn, a3, bv.w);

        float ss = a0 * a0 + a1 * a1 + a2 * a2 + a3 * a3;
        ss += __shfl_xor(ss, 1, 64);
        ss += __shfl_xor(ss, 2, 64);
        ss += __shfl_xor(ss, 4, 64);
        ss += __shfl_xor(ss, 8, 64);
        float inv = 1.0f / fmaxf(sqrtf(ss), 1e-12f);
        a0 = fmaxf(a0 * inv, 0.f);
        a1 = fmaxf(a1 * inv, 0.f);
        a2 = fmaxf(a2 * inv, 0.f);
        a3 = fmaxf(a3 * inv, 0.f);

        if (act) {
            if (F32OUT) {
                float4 o = {a0, a1, a2, a3};
                *(float4*)(Qf + (size_t)nd * 64 + fl * 4) = o;
            } else {
                bf16x4 o;
                o[0] = (bf16_t)a0; o[1] = (bf16_t)a1;
                o[2] = (bf16_t)a2; o[3] = (bf16_t)a3;
                *(bf16x4*)(Qb + (size_t)nd * 64 + fl * 4) = o;
            }
        }
    }
}

// ---------------- segmented pool (batch sorted) ----------------

__global__ void k_starts(const int* __restrict__ batch, int* __restrict__ starts,
                         int N, int G) {
    int g = blockIdx.x * blockDim.x + threadIdx.x;
    if (g > G) return;
    int lo = 0, hi = N;
    while (lo < hi) {
        int mid = (lo + hi) >> 1;
        if (batch[mid] < g) lo = mid + 1; else hi = mid;
    }
    starts[g] = lo;
}

// one 512-thread block per graph; t&15 = feature quad, t>>4 = row group (32-way)
__global__ __launch_bounds__(512) void k_pool(const float* __restrict__ Q,
        const int* __restrict__ starts, float* __restrict__ pooled, int G) {
    __shared__ float4 red[8][16];
    int g = blockIdx.x;
    int t = threadIdx.x;
    int fl = t & 15;
    int rg = t >> 4;          // 0..31
    int beg = starts[g], end = starts[g + 1];
    float4 acc = {0.f, 0.f, 0.f, 0.f};
    int i = beg + rg;
    for (; i + 32 < end; i += 64) {
        float4 v0 = *(const float4*)(Q + (size_t)i * 64 + fl * 4);
        float4 v1 = *(const float4*)(Q + (size_t)(i + 32) * 64 + fl * 4);
        acc.x += v0.x + v1.x; acc.y += v0.y + v1.y;
        acc.z += v0.z + v1.z; acc.w += v0.w + v1.w;
    }
    if (i < end) {
        float4 v = *(const float4*)(Q + (size_t)i * 64 + fl * 4);
        acc.x += v.x; acc.y += v.y; acc.z += v.z; acc.w += v.w;
    }
    acc.x += __shfl_xor(acc.x, 16, 64); acc.y += __shfl_xor(acc.y, 16, 64);
    acc.z += __shfl_xor(acc.z, 16, 64); acc.w += __shfl_xor(acc.w, 16, 64);
    acc.x += __shfl_xor(acc.x, 32, 64); acc.y += __shfl_xor(acc.y, 32, 64);
    acc.z += __shfl_xor(acc.z, 32, 64); acc.w += __shfl_xor(acc.w, 32, 64);
    int w = t >> 6;
    if ((t & 63) < 16) red[w][fl] = acc;
    __syncthreads();
    if (t < 16) {
        float4 s = red[0][t];
#pragma unroll
        for (int j = 1; j < 8; ++j) {
            float4 v = red[j][t];
            s.x += v.x; s.y += v.y; s.z += v.z; s.w += v.w;
        }
        *(float4*)(pooled + (size_t)g * 64 + t * 4) = s;
    }
}

// ---------------- per-graph MLP + log_softmax ----------------

__global__ void k_mlp(const float* __restrict__ pooled,
                      const float* __restrict__ fc1w, const float* __restrict__ fc1b,
                      const float* __restrict__ fc2w, const float* __restrict__ fc2b,
                      float* __restrict__ out, int G) {
    __shared__ float sp[64];
    __shared__ float sz[64];
    __shared__ float sl[10];
    __shared__ float slse;
    int g = blockIdx.x;
    int t = threadIdx.x;
    if (g >= G) return;
    sp[t] = pooled[(size_t)g * 64 + t];
    __syncthreads();
    float acc = fc1b[t];
#pragma unroll
    for (int k = 0; k < 64; ++k) acc += sp[k] * fc1w[k * 64 + t];
    sz[t] = fmaxf(acc, 0.f);
    __syncthreads();
    if (t < 10) {
        float a = fc2b[t];
#pragma unroll
        for (int j = 0; j < 64; ++j) a += sz[j] * fc2w[j * 10 + t];
        sl[t] = a;
    }
    __syncthreads();
    if (t == 0) {
        float m = sl[0];
        for (int c = 1; c < 10; ++c) m = fmaxf(m, sl[c]);
        float s = 0.f;
        for (int c = 0; c < 10; ++c) s += expf(sl[c] - m);
        slse = m + logf(s);
    }
    __syncthreads();
    if (t < 10) out[(size_t)g * 10 + t] = sl[t] - slse;
}

// ---------------- launch ----------------

extern "C" void kernel_launch(void* const* d_in, const int* in_sizes, int n_in,
                              void* d_out, int out_size, void* d_ws, size_t ws_size,
                              hipStream_t stream) {
    const float* x     = (const float*)d_in[0];
    const int*   ei    = (const int*)d_in[1];
    const int*   batch = (const int*)d_in[2];
    const float* ew    = (const float*)d_in[3];
    const float* W1 = (const float*)d_in[4];
    const float* b1 = (const float*)d_in[5];
    const float* W2 = (const float*)d_in[6];
    const float* b2 = (const float*)d_in[7];
    const float* W3 = (const float*)d_in[8];
    const float* b3 = (const float*)d_in[9];
    const float* fc1w = (const float*)d_in[10];
    const float* fc1b = (const float*)d_in[11];
    const float* fc2w = (const float*)d_in[12];
    const float* fc2b = (const float*)d_in[13];
    float* out = (float*)d_out;

    const int N = in_sizes[0] / 128;   // 100000 (multiple of 16)
    const int E = in_sizes[1] / 2;     // 3200000
    const int G = out_size / 10;       // 512
    const int NB = (N + (1 << BSH) - 1) >> BSH;   // 196 buckets of 512 nodes

    // workspace (256B-aligned chunks)
    char* wp = (char*)d_ws;
    auto alloc = [&](size_t bytes) {
        char* p = wp;
        wp += (bytes + 255) & ~(size_t)255;
        return p;
    };
    size_t qbytes = (size_t)N * 64 * 4;
    size_t rbytes = (size_t)NB * CAP * 8;
    // Q region double-duty: padded rec first, then conv outputs (rec dead by then)
    char*   Qreg    = alloc(qbytes > rbytes ? qbytes : rbytes);
    float*  Qf      = (float*)Qreg;
    bf16_t* Qb      = (bf16_t*)Qreg;
    int2*   rec     = (int2*)Qreg;
    bf16_t* P       = (bf16_t*)alloc((size_t)N * 64 * 2);
    int2*   meta    = (int2*) alloc(rbytes);          // padded, indexed via rbeg/rend
    int*    rbeg    = (int*)  alloc((size_t)N * 4);
    int*    rend    = (int*)  alloc((size_t)N * 4);
    float*  dinv    = (float*)alloc((size_t)N * 4);
    float*  pooled  = (float*)alloc((size_t)G * 64 * 4);
    int*    starts  = (int*)  alloc((size_t)(G + 1) * 4);
    int*    bcur    = (int*)  alloc((size_t)NB * 4);

    dim3 blk(256);
    dim3 g1024(1024);
    const int ntiles = N / 16;                         // 6250
    const int nblkB  = (E + BTILE - 1) / BTILE;        // 391
    const int nquads = (N + 3) / 4;                    // 25000
    dim3 gconv((nquads + 3) / 4);                      // 6250 blocks, 1 quad/wave

    // CSR build: bin into padded buckets -> per-bucket sort (+dinv, rbeg/rend)
    k_fill_i<<<dim3(1), blk, 0, stream>>>(bcur, 0, NB);
    k_passB<<<dim3(nblkB), dim3(512), 0, stream>>>(ei, ew, bcur, rec, E, NB);
    k_passC<<<dim3(NB), dim3(1024), 0, stream>>>(rec, bcur, rbeg, rend, dinv, meta, N);
    k_starts<<<dim3(4), blk, 0, stream>>>(batch, starts, N, G);

    // conv1 (K=128, f32 A)   [rec region is dead from here on; Q reuses it]
    k_gemm_mfma<128, true><<<g1024, blk, 0, stream>>>(x, W1, dinv, P, ntiles);
    k_conv4<false><<<gconv, blk, 0, stream>>>(P, rbeg, rend, meta, dinv, b1, Qb, nullptr, N);
    // conv2 (K=64, bf16 A)
    k_gemm_mfma<64, false><<<g1024, blk, 0, stream>>>(Qb, W2, dinv, P, ntiles);
    k_conv4<false><<<gconv, blk, 0, stream>>>(P, rbeg, rend, meta, dinv, b2, Qb, nullptr, N);
    // conv3 (K=64, bf16 A, f32 node output for pooling)
    k_gemm_mfma<64, false><<<g1024, blk, 0, stream>>>(Qb, W3, dinv, P, ntiles);
    k_conv4<true><<<gconv, blk, 0, stream>>>(P, rbeg, rend, meta, dinv, b3, nullptr, Qf, N);

    // pool + MLP
    k_pool<<<dim3(G), dim3(512), 0, stream>>>(Qf, starts, pooled, G);
    k_mlp<<<dim3(G), dim3(64), 0, stream>>>(pooled, fc1w, fc1b, fc2w, fc2b, out, G);
}

// Round 11
// 354.527 us; speedup vs baseline: 1.0734x; 1.0734x over previous
//
#include <hip/hip_runtime.h>
#include <math.h>

typedef __bf16 bf16_t;
typedef __attribute__((ext_vector_type(4))) __bf16 bf16x4;
typedef __attribute__((ext_vector_type(8))) __bf16 bf16x8;
typedef __attribute__((ext_vector_type(4))) float f32x4;

#define BTILE 8192      // edges per passB tile
#define BSH   9         // bucket shift: 512 nodes per bucket
#define CAP   18432     // record capacity per bucket (mean 16384 + 16 sigma)

// ---------------- Pass B: bin edges into capacity-padded buckets ----------------
// record.x = (dst&511)<<17 | src  (src < 2^17), record.y = ew bits

__global__ __launch_bounds__(512) void k_passB(const int* __restrict__ ei,
        const float* __restrict__ ew, int* __restrict__ bcur,
        int2* __restrict__ rec, int E, int NB) {
    __shared__ int lhist[256];
    __shared__ int base[256];
    const int* dstp = ei + E;
    int tile0 = blockIdx.x * BTILE;
    int t = threadIdx.x;
    if (t < 256) lhist[t] = 0;
    __syncthreads();
    int rank[BTILE / 512];
#pragma unroll
    for (int j = 0; j < BTILE / 512; ++j) {
        int e = tile0 + j * 512 + t;
        if (e < E) rank[j] = atomicAdd(&lhist[dstp[e] >> BSH], 1);
    }
    __syncthreads();
    if (t < NB) {
        int c = lhist[t];
        base[t] = c ? atomicAdd(&bcur[t], c) : 0;
    }
    __syncthreads();
#pragma unroll
    for (int j = 0; j < BTILE / 512; ++j) {
        int e = tile0 + j * 512 + t;
        if (e < E) {
            int d = dstp[e];
            int b = d >> BSH;
            rec[(size_t)b * CAP + base[b] + rank[j]] =
                make_int2(((d & 511) << 17) | ei[e], __float_as_int(ew[e]));
        }
    }
}

// ---------------- Pass C: per-bucket counting sort -> meta, rbeg/rend, dinv ----

__global__ __launch_bounds__(1024) void k_passC(const int2* __restrict__ rec,
        const int* __restrict__ bcur, int* __restrict__ rbeg, int* __restrict__ rend,
        float* __restrict__ dinv, int2* __restrict__ meta, int N) {
    __shared__ int   nh[512];
    __shared__ float sw[512];
    __shared__ int   offs[512];
    __shared__ int   cur[512];
    __shared__ int   scn[512];
    int b = blockIdx.x, t = threadIdx.x;
    if (t < 512) { nh[t] = 0; sw[t] = 0.f; cur[t] = 0; }
    __syncthreads();
    int len = bcur[b];
    size_t rs = (size_t)b * CAP;
    for (int i = t; i < len; i += 1024) {
        int2 r = rec[rs + i];
        int dl = r.x >> 17;
        atomicAdd(&nh[dl], 1);
        atomicAdd(&sw[dl], __int_as_float(r.y));
    }
    __syncthreads();
    if (t < 512) scn[t] = nh[t];
    __syncthreads();
    for (int off = 1; off < 512; off <<= 1) {
        int v = (t >= off && t < 512) ? scn[t - off] : 0;
        __syncthreads();
        if (t < 512) scn[t] += v;
        __syncthreads();
    }
    if (t < 512) {
        offs[t] = scn[t] - nh[t];
        int node = (b << BSH) + t;
        if (node < N) {
            int rb = (int)rs + offs[t];
            rbeg[node] = rb;
            rend[node] = rb + nh[t];
            dinv[node] = rsqrtf(1.f + sw[t]);
        }
    }
    __syncthreads();
    for (int i = t; i < len; i += 1024) {
        int2 r = rec[rs + i];
        int dl = r.x >> 17;
        int pos = atomicAdd(&cur[dl], 1);
        meta[rs + offs[dl] + pos] = make_int2(r.x & 0x1FFFF, r.y);
    }
}

// ---------------- MFMA GEMM: out[n][f] = dinv[n] * (X[n][:] @ W[:][f]) ----------------

template <int K, bool A_F32>
__global__ __launch_bounds__(256) void k_gemm_mfma(
        const void* __restrict__ Xv, const float* __restrict__ W,
        const float* __restrict__ dinv, bf16_t* __restrict__ outb, int ntiles) {
    __shared__ bf16_t sWt[64 * K];              // transposed W: sWt[c*K + k]
    for (int idx = threadIdx.x; idx < K * 64; idx += blockDim.x) {
        int k = idx >> 6, c = idx & 63;
        sWt[c * K + k] = (bf16_t)W[idx];
    }
    __syncthreads();

    int lane = threadIdx.x & 63;
    int wid  = threadIdx.x >> 6;
    int colbase = wid * 16;
    int lm = lane & 15;
    int lk = lane >> 4;

    bf16x8 bfrag[K / 32];
#pragma unroll
    for (int ks = 0; ks < K / 32; ++ks)
        bfrag[ks] = *(const bf16x8*)&sWt[(colbase + lm) * K + ks * 32 + lk * 8];

    const float*  Xf = (const float*)Xv;
    const bf16_t* Xb = (const bf16_t*)Xv;

    for (int t = blockIdx.x; t < ntiles; t += gridDim.x) {
        f32x4 acc = {0.f, 0.f, 0.f, 0.f};
        size_t rowoff = (size_t)(t * 16 + lm) * K + lk * 8;
#pragma unroll
        for (int ks = 0; ks < K / 32; ++ks) {
            bf16x8 afrag;
            if (A_F32) {
                float4 v0 = *(const float4*)(Xf + rowoff + ks * 32);
                float4 v1 = *(const float4*)(Xf + rowoff + ks * 32 + 4);
                afrag[0] = (bf16_t)v0.x; afrag[1] = (bf16_t)v0.y;
                afrag[2] = (bf16_t)v0.z; afrag[3] = (bf16_t)v0.w;
                afrag[4] = (bf16_t)v1.x; afrag[5] = (bf16_t)v1.y;
                afrag[6] = (bf16_t)v1.z; afrag[7] = (bf16_t)v1.w;
            } else {
                afrag = *(const bf16x8*)(Xb + rowoff + ks * 32);
            }
            acc = __builtin_amdgcn_mfma_f32_16x16x32_bf16(afrag, bfrag[ks], acc, 0, 0, 0);
        }
#pragma unroll
        for (int r = 0; r < 4; ++r) {
            int row = t * 16 + lk * 4 + r;
            outb[(size_t)row * 64 + colbase + lm] = (bf16_t)(acc[r] * dinv[row]);
        }
    }
}

// ---------------- fused gather-conv, 4 nodes per wave, 4 edges/iter (round-9 form) ----

template <bool F32OUT>
__global__ __launch_bounds__(256) void k_conv4(
        const bf16_t* __restrict__ P, const int* __restrict__ rbeg,
        const int* __restrict__ rend,
        const int2* __restrict__ meta, const float* __restrict__ dinv,
        const float* __restrict__ b, bf16_t* __restrict__ Qb,
        float* __restrict__ Qf, int n_nodes) {
    int lane = threadIdx.x & 63;
    int g  = lane >> 4;
    int fl = lane & 15;
    int wave  = blockIdx.x * (blockDim.x >> 6) + (threadIdx.x >> 6);
    int nwave = gridDim.x * (blockDim.x >> 6);
    int nquads = (n_nodes + 3) >> 2;

    float4 bv = *(const float4*)(b + fl * 4);

    for (int q = wave; q < nquads; q += nwave) {
        int nd = q * 4 + g;
        bool act = nd < n_nodes;
        int ndc = act ? nd : 0;

        int beg = rbeg[ndc];
        int end = rend[ndc];

        bf16x4 sv = *(const bf16x4*)(P + (size_t)ndc * 64 + fl * 4);
        float a0 = (float)sv[0], a1 = (float)sv[1], a2 = (float)sv[2], a3 = (float)sv[3];
        float c0 = 0.f, c1 = 0.f, c2 = 0.f, c3 = 0.f;

        int e = beg;
        if ((e & 1) && e < end) {                 // align to int4
            int2 m = meta[e];
            bf16x4 p = *(const bf16x4*)(P + (size_t)m.x * 64 + fl * 4);
            float w = __int_as_float(m.y);
            a0 = fmaf(w, (float)p[0], a0);
            a1 = fmaf(w, (float)p[1], a1);
            a2 = fmaf(w, (float)p[2], a2);
            a3 = fmaf(w, (float)p[3], a3);
            ++e;
        }
        for (; e + 3 < end; e += 4) {
            int4 A = *(const int4*)&meta[e];
            int4 B = *(const int4*)&meta[e + 2];
            bf16x4 p0 = *(const bf16x4*)(P + (size_t)A.x * 64 + fl * 4);
            bf16x4 p1 = *(const bf16x4*)(P + (size_t)A.z * 64 + fl * 4);
            bf16x4 p2 = *(const bf16x4*)(P + (size_t)B.x * 64 + fl * 4);
            bf16x4 p3 = *(const bf16x4*)(P + (size_t)B.z * 64 + fl * 4);
            float w0 = __int_as_float(A.y);
            float w1 = __int_as_float(A.w);
            float w2 = __int_as_float(B.y);
            float w3 = __int_as_float(B.w);
            a0 = fmaf(w0, (float)p0[0], a0);
            a1 = fmaf(w0, (float)p0[1], a1);
            a2 = fmaf(w0, (float)p0[2], a2);
            a3 = fmaf(w0, (float)p0[3], a3);
            c0 = fmaf(w1, (float)p1[0], c0);
            c1 = fmaf(w1, (float)p1[1], c1);
            c2 = fmaf(w1, (float)p1[2], c2);
            c3 = fmaf(w1, (float)p1[3], c3);
            a0 = fmaf(w2, (float)p2[0], a0);
            a1 = fmaf(w2, (float)p2[1], a1);
            a2 = fmaf(w2, (float)p2[2], a2);
            a3 = fmaf(w2, (float)p2[3], a3);
            c0 = fmaf(w3, (float)p3[0], c0);
            c1 = fmaf(w3, (float)p3[1], c1);
            c2 = fmaf(w3, (float)p3[2], c2);
            c3 = fmaf(w3, (float)p3[3], c3);
        }
        if (e + 1 < end) {
            int4 A = *(const int4*)&meta[e];
            bf16x4 p0 = *(const bf16x4*)(P + (size_t)A.x * 64 + fl * 4);
            bf16x4 p1 = *(const bf16x4*)(P + (size_t)A.z * 64 + fl * 4);
            float w0 = __int_as_float(A.y);
            float w1 = __int_as_float(A.w);
            a0 = fmaf(w0, (float)p0[0], a0);
            a1 = fmaf(w0, (float)p0[1], a1);
            a2 = fmaf(w0, (float)p0[2], a2);
            a3 = fmaf(w0, (float)p0[3], a3);
            c0 = fmaf(w1, (float)p1[0], c0);
            c1 = fmaf(w1, (float)p1[1], c1);
            c2 = fmaf(w1, (float)p1[2], c2);
            c3 = fmaf(w1, (float)p1[3], c3);
            e += 2;
        }
        if (e < end) {
            int2 m = meta[e];
            bf16x4 p = *(const bf16x4*)(P + (size_t)m.x * 64 + fl * 4);
            float w = __int_as_float(m.y);
            a0 = fmaf(w, (float)p[0], a0);
            a1 = fmaf(w, (float)p[1], a1);
            a2 = fmaf(w, (float)p[2], a2);
            a3 = fmaf(w, (float)p[3], a3);
        }
        a0 += c0; a1 += c1; a2 += c2; a3 += c3;

        float dn = dinv[ndc];
        a0 = fmaf(dn, a0, bv.x);
        a1 = fmaf(dn, a1, bv.y);
        a2 = fmaf(dn, a2, bv.z);
        a3 = fmaf(dn, a3, bv.w);

        float ss = a0 * a0 + a1 * a1 + a2 * a2 + a3 * a3;
        ss += __shfl_xor(ss, 1, 64);
        ss += __shfl_xor(ss, 2, 64);
        ss += __shfl_xor(ss, 4, 64);
        ss += __shfl_xor(ss, 8, 64);
        float inv = 1.0f / fmaxf(sqrtf(ss), 1e-12f);
        a0 = fmaxf(a0 * inv, 0.f);
        a1 = fmaxf(a1 * inv, 0.f);
        a2 = fmaxf(a2 * inv, 0.f);
        a3 = fmaxf(a3 * inv, 0.f);

        if (act) {
            if (F32OUT) {
                float4 o = {a0, a1, a2, a3};
                *(float4*)(Qf + (size_t)nd * 64 + fl * 4) = o;
            } else {
                bf16x4 o;
                o[0] = (bf16_t)a0; o[1] = (bf16_t)a1;
                o[2] = (bf16_t)a2; o[3] = (bf16_t)a3;
                *(bf16x4*)(Qb + (size_t)nd * 64 + fl * 4) = o;
            }
        }
    }
}

// ---------------- segment starts (batch sorted) ----------------

__global__ void k_starts(const int* __restrict__ batch, int* __restrict__ starts,
                         int N, int G) {
    int g = blockIdx.x * blockDim.x + threadIdx.x;
    if (g > G) return;
    int lo = 0, hi = N;
    while (lo < hi) {
        int mid = (lo + hi) >> 1;
        if (batch[mid] < g) lo = mid + 1; else hi = mid;
    }
    starts[g] = lo;
}

// ---------------- fused pool + MLP + log_softmax: one 512-thread block per graph ----
// phase 1: t&15 = feature quad, t>>4 = row group (32-way) -> sp[64] in LDS
// phase 2: t<64 does fc1 col t; t<10 fc2; t==0 lse; t<10 writes.

__global__ __launch_bounds__(512) void k_pool_mlp(const float* __restrict__ Q,
        const int* __restrict__ starts,
        const float* __restrict__ fc1w, const float* __restrict__ fc1b,
        const float* __restrict__ fc2w, const float* __restrict__ fc2b,
        float* __restrict__ out, int G) {
    __shared__ float4 red[8][16];
    __shared__ float sp[64];
    __shared__ float sz[64];
    __shared__ float sl[10];
    __shared__ float slse;
    int g = blockIdx.x;
    int t = threadIdx.x;
    int fl = t & 15;
    int rg = t >> 4;          // 0..31
    int beg = starts[g], end = starts[g + 1];
    float4 acc = {0.f, 0.f, 0.f, 0.f};
    int i = beg + rg;
    for (; i + 32 < end; i += 64) {
        float4 v0 = *(const float4*)(Q + (size_t)i * 64 + fl * 4);
        float4 v1 = *(const float4*)(Q + (size_t)(i + 32) * 64 + fl * 4);
        acc.x += v0.x + v1.x; acc.y += v0.y + v1.y;
        acc.z += v0.z + v1.z; acc.w += v0.w + v1.w;
    }
    if (i < end) {
        float4 v = *(const float4*)(Q + (size_t)i * 64 + fl * 4);
        acc.x += v.x; acc.y += v.y; acc.z += v.z; acc.w += v.w;
    }
    acc.x += __shfl_xor(acc.x, 16, 64); acc.y += __shfl_xor(acc.y, 16, 64);
    acc.z += __shfl_xor(acc.z, 16, 64); acc.w += __shfl_xor(acc.w, 16, 64);
    acc.x += __shfl_xor(acc.x, 32, 64); acc.y += __shfl_xor(acc.y, 32, 64);
    acc.z += __shfl_xor(acc.z, 32, 64); acc.w += __shfl_xor(acc.w, 32, 64);
    int w = t >> 6;
    if ((t & 63) < 16) red[w][fl] = acc;
    __syncthreads();
    if (t < 16) {
        float4 s = red[0][t];
#pragma unroll
        for (int j = 1; j < 8; ++j) {
            float4 v = red[j][t];
            s.x += v.x; s.y += v.y; s.z += v.z; s.w += v.w;
        }
        sp[t * 4 + 0] = s.x; sp[t * 4 + 1] = s.y;
        sp[t * 4 + 2] = s.z; sp[t * 4 + 3] = s.w;
    }
    __syncthreads();
    if (t < 64) {
        float a = fc1b[t];
#pragma unroll
        for (int k = 0; k < 64; ++k) a += sp[k] * fc1w[k * 64 + t];
        sz[t] = fmaxf(a, 0.f);
    }
    __syncthreads();
    if (t < 10) {
        float a = fc2b[t];
#pragma unroll
        for (int j = 0; j < 64; ++j) a += sz[j] * fc2w[j * 10 + t];
        sl[t] = a;
    }
    __syncthreads();
    if (t == 0) {
        float m = sl[0];
        for (int c = 1; c < 10; ++c) m = fmaxf(m, sl[c]);
        float s = 0.f;
        for (int c = 0; c < 10; ++c) s += expf(sl[c] - m);
        slse = m + logf(s);
    }
    __syncthreads();
    if (t < 10) out[(size_t)g * 10 + t] = sl[t] - slse;
}

// ---------------- launch ----------------

extern "C" void kernel_launch(void* const* d_in, const int* in_sizes, int n_in,
                              void* d_out, int out_size, void* d_ws, size_t ws_size,
                              hipStream_t stream) {
    const float* x     = (const float*)d_in[0];
    const int*   ei    = (const int*)d_in[1];
    const int*   batch = (const int*)d_in[2];
    const float* ew    = (const float*)d_in[3];
    const float* W1 = (const float*)d_in[4];
    const float* b1 = (const float*)d_in[5];
    const float* W2 = (const float*)d_in[6];
    const float* b2 = (const float*)d_in[7];
    const float* W3 = (const float*)d_in[8];
    const float* b3 = (const float*)d_in[9];
    const float* fc1w = (const float*)d_in[10];
    const float* fc1b = (const float*)d_in[11];
    const float* fc2w = (const float*)d_in[12];
    const float* fc2b = (const float*)d_in[13];
    float* out = (float*)d_out;

    const int N = in_sizes[0] / 128;   // 100000 (multiple of 16)
    const int E = in_sizes[1] / 2;     // 3200000
    const int G = out_size / 10;       // 512
    const int NB = (N + (1 << BSH) - 1) >> BSH;   // 196 buckets of 512 nodes

    // workspace (256B-aligned chunks)
    char* wp = (char*)d_ws;
    auto alloc = [&](size_t bytes) {
        char* p = wp;
        wp += (bytes + 255) & ~(size_t)255;
        return p;
    };
    size_t qbytes = (size_t)N * 64 * 4;
    size_t rbytes = (size_t)NB * CAP * 8;
    // Q region double-duty: padded rec first, then conv outputs (rec dead by then)
    char*   Qreg    = alloc(qbytes > rbytes ? qbytes : rbytes);
    float*  Qf      = (float*)Qreg;
    bf16_t* Qb      = (bf16_t*)Qreg;
    int2*   rec     = (int2*)Qreg;
    bf16_t* P       = (bf16_t*)alloc((size_t)N * 64 * 2);
    int2*   meta    = (int2*) alloc(rbytes);          // padded, indexed via rbeg/rend
    int*    rbeg    = (int*)  alloc((size_t)N * 4);
    int*    rend    = (int*)  alloc((size_t)N * 4);
    float*  dinv    = (float*)alloc((size_t)N * 4);
    int*    starts  = (int*)  alloc((size_t)(G + 1) * 4);
    int*    bcur    = (int*)  alloc((size_t)NB * 4);

    dim3 blk(256);
    dim3 g1024(1024);
    const int ntiles = N / 16;                         // 6250
    const int nblkB  = (E + BTILE - 1) / BTILE;        // 391
    const int nquads = (N + 3) / 4;                    // 25000
    dim3 gconv((nquads + 3) / 4);                      // 6250 blocks, 1 quad/wave

    // CSR build: bin into padded buckets -> per-bucket sort (+dinv, rbeg/rend)
    hipMemsetAsync(bcur, 0, (size_t)NB * 4, stream);
    k_passB<<<dim3(nblkB), dim3(512), 0, stream>>>(ei, ew, bcur, rec, E, NB);
    k_passC<<<dim3(NB), dim3(1024), 0, stream>>>(rec, bcur, rbeg, rend, dinv, meta, N);
    k_starts<<<dim3(4), blk, 0, stream>>>(batch, starts, N, G);

    // conv1 (K=128, f32 A)   [rec region is dead from here on; Q reuses it]
    k_gemm_mfma<128, true><<<g1024, blk, 0, stream>>>(x, W1, dinv, P, ntiles);
    k_conv4<false><<<gconv, blk, 0, stream>>>(P, rbeg, rend, meta, dinv, b1, Qb, nullptr, N);
    // conv2 (K=64, bf16 A)
    k_gemm_mfma<64, false><<<g1024, blk, 0, stream>>>(Qb, W2, dinv, P, ntiles);
    k_conv4<false><<<gconv, blk, 0, stream>>>(P, rbeg, rend, meta, dinv, b2, Qb, nullptr, N);
    // conv3 (K=64, bf16 A, f32 node output for pooling)
    k_gemm_mfma<64, false><<<g1024, blk, 0, stream>>>(Qb, W3, dinv, P, ntiles);
    k_conv4<true><<<gconv, blk, 0, stream>>>(P, rbeg, rend, meta, dinv, b3, nullptr, Qf, N);

    // fused pool + MLP
    k_pool_mlp<<<dim3(G), dim3(512), 0, stream>>>(Qf, starts, fc1w, fc1b, fc2w, fc2b, out, G);
}